// Round 1
// baseline (553.692 us; speedup 1.0000x reference)
//
#include <hip/hip_runtime.h>

#define NF   512
#define HIDD 16

__device__ inline float4 f4add(float4 a, float4 b){
  return make_float4(a.x+b.x, a.y+b.y, a.z+b.z, a.w+b.w);
}
__device__ inline float4 f4fma(float4 a, float s, float4 b){
  return make_float4(fmaf(s,b.x,a.x), fmaf(s,b.y,a.y), fmaf(s,b.z,a.z), fmaf(s,b.w,a.w));
}

// ---- dtype probe: int64 edge_index has all odd 32-bit words == 0 ----
__global__ __launch_bounds__(256) void k_detect(const int* __restrict__ ei, int* __restrict__ flag){
  __shared__ int any;
  if (threadIdx.x == 0) any = 0;
  __syncthreads();
  int found = 0;
  for (int i = 1 + 2*(int)threadIdx.x; i < 8192; i += 512) found |= (ei[i] != 0);
  if (found) any = 1;      // benign race, all write 1
  __syncthreads();
  if (threadIdx.x == 0) flag[0] = any ? 0 : 1;   // 1 => int64 layout
}

__global__ __launch_bounds__(256) void k_zero(int* __restrict__ degi, int N){
  int i = blockIdx.x*256 + threadIdx.x;
  if (i < N) degi[i] = 0;
}

__global__ __launch_bounds__(256) void k_hist(const int* __restrict__ ei, const int* __restrict__ flag,
                                              int E, int* __restrict__ degi){
  int e = blockIdx.x*256 + threadIdx.x;
  if (e >= E) return;
  int is64 = flag[0];
  int c = is64 ? ei[2*(E+e)] : ei[E+e];
  atomicAdd(&degi[c], 1);
}

__global__ __launch_bounds__(256) void k_dis(const int* __restrict__ degi, float* __restrict__ dis, int N){
  int i = blockIdx.x*256 + threadIdx.x;
  if (i < N) dis[i] = rsqrtf((float)(degi[i] + 1));   // +1 self-loop; deg>=1 always
}

// ---- exclusive scan of degi -> offs (chunk=1024/block) ----
__global__ __launch_bounds__(256) void k_scanA(const int* __restrict__ degi, int N, int* __restrict__ bsum){
  __shared__ int sd[256];
  int t = threadIdx.x;
  int base = blockIdx.x*1024 + t*4;
  int s = 0;
  #pragma unroll
  for (int j = 0; j < 4; ++j){ int i = base + j; s += (i < N) ? degi[i] : 0; }
  sd[t] = s; __syncthreads();
  for (int off = 128; off > 0; off >>= 1){
    if (t < off) sd[t] += sd[t + off];
    __syncthreads();
  }
  if (t == 0) bsum[blockIdx.x] = sd[0];
}

__global__ __launch_bounds__(128) void k_scanB(const int* __restrict__ bsum, int nb, int* __restrict__ boff){
  __shared__ int sd[128];
  int t = threadIdx.x;
  int v = (t < nb) ? bsum[t] : 0;
  sd[t] = v; __syncthreads();
  for (int off = 1; off < 128; off <<= 1){
    int a = sd[t];
    int u = (t >= off) ? sd[t - off] : 0;
    __syncthreads();
    sd[t] = a + u;
    __syncthreads();
  }
  if (t < nb) boff[t] = sd[t] - v;
}

__global__ __launch_bounds__(256) void k_scanC(const int* __restrict__ degi, int N,
                                               const int* __restrict__ boff,
                                               int* __restrict__ offs, int* __restrict__ cur){
  __shared__ int sd[256];
  int t = threadIdx.x;
  int base = blockIdx.x*1024 + t*4;
  int d0 = (base+0 < N) ? degi[base+0] : 0;
  int d1 = (base+1 < N) ? degi[base+1] : 0;
  int d2 = (base+2 < N) ? degi[base+2] : 0;
  int d3 = (base+3 < N) ? degi[base+3] : 0;
  int s = d0 + d1 + d2 + d3;
  sd[t] = s; __syncthreads();
  for (int off = 1; off < 256; off <<= 1){
    int a = sd[t];
    int u = (t >= off) ? sd[t - off] : 0;
    __syncthreads();
    sd[t] = a + u;
    __syncthreads();
  }
  int p0 = sd[t] - s + boff[blockIdx.x];
  int p1 = p0 + d0, p2 = p1 + d1, p3 = p2 + d2;
  if (base+0 < N){ offs[base+0] = p0; cur[base+0] = p0; }
  if (base+1 < N){ offs[base+1] = p1; cur[base+1] = p1; }
  if (base+2 < N){ offs[base+2] = p2; cur[base+2] = p2; }
  if (base+3 < N){ offs[base+3] = p3; cur[base+3] = p3; }
}

__global__ __launch_bounds__(256) void k_fill(const int* __restrict__ ei, const int* __restrict__ flag,
                                              int E, int* __restrict__ cur, int* __restrict__ csr){
  int e = blockIdx.x*256 + threadIdx.x;
  if (e >= E) return;
  int is64 = flag[0];
  int r, c;
  if (is64){ r = ei[2*e]; c = ei[2*(E+e)]; }
  else     { r = ei[e];   c = ei[E+e];     }
  int pos = atomicAdd(&cur[c], 1);
  csr[pos] = r;
}

// ---- hs1 = dis * (x @ W1); BM=256 rows/block, BK=32, thread tile 4x4 ----
__global__ __launch_bounds__(256) void k_gemm1(const float* __restrict__ x, const float* __restrict__ W1,
                                               const float* __restrict__ dis, float* __restrict__ hs1, int N){
  __shared__ float xs[256*36];     // pad 32->36 (16B aligned, 2-way max conflict)
  __shared__ float wc[32*16];
  int t  = threadIdx.x;
  int R0 = blockIdx.x*256;
  int lr = t >> 3;                 // 0..31 (load row group)
  int lc = (t & 7) * 4;            // 0..28 (load col within 32-chunk)
  int rt = t >> 2;                 // 0..63 compute row group (rows rt*4+m)
  int jq = t & 3;                  // col quad (cols jq*4..+3)

  float4 acc0 = make_float4(0,0,0,0), acc1 = acc0, acc2 = acc0, acc3 = acc0;

  for (int kc = 0; kc < NF; kc += 32){
    #pragma unroll
    for (int li = 0; li < 8; ++li){
      int row = lr + li*32;
      int gr  = R0 + row;
      int grc = (gr < N) ? gr : 0;
      float4 v = *(const float4*)(x + (size_t)grc*NF + kc + lc);
      *(float4*)(xs + row*36 + lc) = v;
    }
    wc[t]       = W1[kc*16 + t];
    wc[t + 256] = W1[kc*16 + t + 256];
    __syncthreads();

    #pragma unroll
    for (int k0 = 0; k0 < 32; k0 += 4){
      float4 xr0 = *(const float4*)(xs + (rt*4+0)*36 + k0);
      float4 xr1 = *(const float4*)(xs + (rt*4+1)*36 + k0);
      float4 xr2 = *(const float4*)(xs + (rt*4+2)*36 + k0);
      float4 xr3 = *(const float4*)(xs + (rt*4+3)*36 + k0);
      float4 w0  = *(const float4*)(wc + (k0+0)*16 + jq*4);
      float4 w1  = *(const float4*)(wc + (k0+1)*16 + jq*4);
      float4 w2  = *(const float4*)(wc + (k0+2)*16 + jq*4);
      float4 w3  = *(const float4*)(wc + (k0+3)*16 + jq*4);
      acc0 = f4fma(acc0, xr0.x, w0); acc0 = f4fma(acc0, xr0.y, w1); acc0 = f4fma(acc0, xr0.z, w2); acc0 = f4fma(acc0, xr0.w, w3);
      acc1 = f4fma(acc1, xr1.x, w0); acc1 = f4fma(acc1, xr1.y, w1); acc1 = f4fma(acc1, xr1.z, w2); acc1 = f4fma(acc1, xr1.w, w3);
      acc2 = f4fma(acc2, xr2.x, w0); acc2 = f4fma(acc2, xr2.y, w1); acc2 = f4fma(acc2, xr2.z, w2); acc2 = f4fma(acc2, xr2.w, w3);
      acc3 = f4fma(acc3, xr3.x, w0); acc3 = f4fma(acc3, xr3.y, w1); acc3 = f4fma(acc3, xr3.z, w2); acc3 = f4fma(acc3, xr3.w, w3);
    }
    __syncthreads();
  }

  #pragma unroll
  for (int m = 0; m < 4; ++m){
    int gr = R0 + rt*4 + m;
    if (gr < N){
      float d = dis[gr];
      float4 a = (m==0)?acc0:(m==1)?acc1:(m==2)?acc2:acc3;
      float4 o = make_float4(a.x*d, a.y*d, a.z*d, a.w*d);
      *(float4*)(hs1 + (size_t)gr*16 + jq*4) = o;
    }
  }
}

// ---- layer1 aggregate + bias/ReLU + layer2 transform: hs2 = dis*(relu(dis*agg+b1) @ W2)
// 2 threads per node (q = half of the 16 features); pair-combined via shfl_xor.
__global__ __launch_bounds__(256) void k_agg1(const float* __restrict__ hs1, const int* __restrict__ offs,
                                              const int* __restrict__ degi, const int* __restrict__ csr,
                                              const float* __restrict__ dis, const float* __restrict__ b1,
                                              const float* __restrict__ W2, float* __restrict__ hs2, int N){
  __shared__ float sW[112];
  __shared__ float sb[16];
  int t = threadIdx.x;
  if (t < 112) sW[t] = W2[t];
  if (t < 16)  sb[t] = b1[t];
  __syncthreads();

  int g = blockIdx.x*256 + t;
  int n = g >> 1, q = g & 1;
  if (n >= N) return;

  const float4* h4 = (const float4*)hs1;
  size_t base = (size_t)n*4 + q*2;
  float4 a0 = h4[base], a1 = h4[base+1];          // self-loop init
  int st = offs[n], cnt = degi[n];
  for (int i = 0; i < cnt; ++i){
    int s = csr[st + i];
    size_t sb4 = (size_t)s*4 + q*2;
    a0 = f4add(a0, h4[sb4]);
    a1 = f4add(a1, h4[sb4+1]);
  }
  float d = dis[n];
  float h[8];
  h[0] = fmaxf(fmaf(d, a0.x, sb[q*8+0]), 0.f);
  h[1] = fmaxf(fmaf(d, a0.y, sb[q*8+1]), 0.f);
  h[2] = fmaxf(fmaf(d, a0.z, sb[q*8+2]), 0.f);
  h[3] = fmaxf(fmaf(d, a0.w, sb[q*8+3]), 0.f);
  h[4] = fmaxf(fmaf(d, a1.x, sb[q*8+4]), 0.f);
  h[5] = fmaxf(fmaf(d, a1.y, sb[q*8+5]), 0.f);
  h[6] = fmaxf(fmaf(d, a1.z, sb[q*8+6]), 0.f);
  h[7] = fmaxf(fmaf(d, a1.w, sb[q*8+7]), 0.f);

  float acc[7] = {0,0,0,0,0,0,0};
  #pragma unroll
  for (int jj = 0; jj < 8; ++jj){
    int j = q*8 + jj;
    #pragma unroll
    for (int c = 0; c < 7; ++c) acc[c] = fmaf(h[jj], sW[j*7 + c], acc[c]);
  }
  #pragma unroll
  for (int c = 0; c < 7; ++c) acc[c] += __shfl_xor(acc[c], 1);

  if (q == 0){
    float4 o = make_float4(acc[0]*d, acc[1]*d, acc[2]*d, acc[3]*d);
    *(float4*)(hs2 + (size_t)n*8) = o;
  } else {
    float4 o = make_float4(acc[4]*d, acc[5]*d, acc[6]*d, 0.f);
    *(float4*)(hs2 + (size_t)n*8 + 4) = o;
  }
}

// ---- layer2 aggregate + bias -> out. 2 threads/node (float4 halves of stride-8 hs2)
__global__ __launch_bounds__(256) void k_agg2(const float* __restrict__ hs2, const int* __restrict__ offs,
                                              const int* __restrict__ degi, const int* __restrict__ csr,
                                              const float* __restrict__ dis, const float* __restrict__ b2,
                                              float* __restrict__ out, int N){
  int g = blockIdx.x*256 + threadIdx.x;
  int n = g >> 1, q = g & 1;
  if (n >= N) return;
  const float4* h4 = (const float4*)hs2;
  float4 a = h4[(size_t)n*2 + q];                 // self-loop init
  int st = offs[n], cnt = degi[n];
  for (int i = 0; i < cnt; ++i){
    int s = csr[st + i];
    a = f4add(a, h4[(size_t)s*2 + q]);
  }
  float d = dis[n];
  float* o = out + (size_t)n*7 + q*4;
  if (q == 0){
    o[0] = fmaf(d, a.x, b2[0]);
    o[1] = fmaf(d, a.y, b2[1]);
    o[2] = fmaf(d, a.z, b2[2]);
    o[3] = fmaf(d, a.w, b2[3]);
  } else {
    o[0] = fmaf(d, a.x, b2[4]);
    o[1] = fmaf(d, a.y, b2[5]);
    o[2] = fmaf(d, a.z, b2[6]);
  }
}

extern "C" void kernel_launch(void* const* d_in, const int* in_sizes, int n_in,
                              void* d_out, int out_size, void* d_ws, size_t ws_size,
                              hipStream_t stream){
  const float* x  = (const float*)d_in[0];
  const int*   ei = (const int*)d_in[1];
  const float* W1 = (const float*)d_in[2];
  const float* b1 = (const float*)d_in[3];
  const float* W2 = (const float*)d_in[4];
  const float* b2 = (const float*)d_in[5];
  float* out = (float*)d_out;

  const int N = in_sizes[0] / NF;      // 100000
  const int E = in_sizes[1] / 2;       // 3200000
  const int nb = (N + 1023) / 1024;    // scan blocks (98, must be <=128)

  // ws carve-up (256B aligned)
  char* w = (char*)d_ws;
  size_t cur = 0;
  auto alloc = [&](size_t bytes)->char*{ char* p = w + cur; cur += (bytes + 255) & ~(size_t)255; return p; };
  int*   flag = (int*)  alloc(256);
  int*   degi = (int*)  alloc((size_t)N*4);
  float* dis  = (float*)alloc((size_t)N*4);
  int*   offs = (int*)  alloc((size_t)N*4);
  int*   curp = (int*)  alloc((size_t)N*4);
  int*   bsum = (int*)  alloc((size_t)nb*4);
  int*   boff = (int*)  alloc((size_t)nb*4);
  int*   csr  = (int*)  alloc((size_t)E*4);
  float* hs1  = (float*)alloc((size_t)N*16*4);
  float* hs2  = (float*)alloc((size_t)N*8*4);
  (void)ws_size; (void)n_in; (void)out_size;

  int gN  = (N + 255) / 256;
  int gE  = (E + 255) / 256;
  int g2N = (2*N + 255) / 256;

  k_detect<<<1, 256, 0, stream>>>(ei, flag);
  k_zero  <<<gN, 256, 0, stream>>>(degi, N);
  k_hist  <<<gE, 256, 0, stream>>>(ei, flag, E, degi);
  k_dis   <<<gN, 256, 0, stream>>>(degi, dis, N);
  k_scanA <<<nb, 256, 0, stream>>>(degi, N, bsum);
  k_scanB <<<1, 128, 0, stream>>>(bsum, nb, boff);
  k_scanC <<<nb, 256, 0, stream>>>(degi, N, boff, offs, curp);
  k_fill  <<<gE, 256, 0, stream>>>(ei, flag, E, curp, csr);
  k_gemm1 <<<gN, 256, 0, stream>>>(x, W1, dis, hs1, N);
  k_agg1  <<<g2N, 256, 0, stream>>>(hs1, offs, degi, csr, dis, b1, W2, hs2, N);
  k_agg2  <<<g2N, 256, 0, stream>>>(hs2, offs, degi, csr, dis, b2, out, N);
}

// Round 2
// 376.706 us; speedup vs baseline: 1.4698x; 1.4698x over previous
//
#include <hip/hip_runtime.h>

#define NF   512
#define HIDD 16

__device__ inline float4 f4add(float4 a, float4 b){
  return make_float4(a.x+b.x, a.y+b.y, a.z+b.z, a.w+b.w);
}
__device__ inline float4 f4fma(float4 a, float s, float4 b){
  return make_float4(fmaf(s,b.x,a.x), fmaf(s,b.y,a.y), fmaf(s,b.z,a.z), fmaf(s,b.w,a.w));
}

// ---- dtype probe: int64 edge_index has all odd 32-bit words == 0 ----
__global__ __launch_bounds__(256) void k_detect(const int* __restrict__ ei, int* __restrict__ flag){
  __shared__ int any;
  if (threadIdx.x == 0) any = 0;
  __syncthreads();
  int found = 0;
  for (int i = 1 + 2*(int)threadIdx.x; i < 8192; i += 512) found |= (ei[i] != 0);
  if (found) any = 1;      // benign race, all write 1
  __syncthreads();
  if (threadIdx.x == 0) flag[0] = any ? 0 : 1;   // 1 => int64 layout
}

__global__ __launch_bounds__(256) void k_zero(int* __restrict__ degi, int N){
  int i = blockIdx.x*256 + threadIdx.x;
  if (i < N) degi[i] = 0;
}

__global__ __launch_bounds__(256) void k_hist(const int* __restrict__ ei, const int* __restrict__ flag,
                                              int E, int* __restrict__ degi){
  int e = blockIdx.x*256 + threadIdx.x;
  if (e >= E) return;
  int is64 = flag[0];
  int c = is64 ? ei[2*(E+e)] : ei[E+e];
  atomicAdd(&degi[c], 1);
}

__global__ __launch_bounds__(256) void k_dis(const int* __restrict__ degi, float* __restrict__ dis, int N){
  int i = blockIdx.x*256 + threadIdx.x;
  if (i < N) dis[i] = rsqrtf((float)(degi[i] + 1));   // +1 self-loop; deg>=1 always
}

// ---- exclusive scan of degi -> offs (chunk=1024/block) ----
__global__ __launch_bounds__(256) void k_scanA(const int* __restrict__ degi, int N, int* __restrict__ bsum){
  __shared__ int sd[256];
  int t = threadIdx.x;
  int base = blockIdx.x*1024 + t*4;
  int s = 0;
  #pragma unroll
  for (int j = 0; j < 4; ++j){ int i = base + j; s += (i < N) ? degi[i] : 0; }
  sd[t] = s; __syncthreads();
  for (int off = 128; off > 0; off >>= 1){
    if (t < off) sd[t] += sd[t + off];
    __syncthreads();
  }
  if (t == 0) bsum[blockIdx.x] = sd[0];
}

__global__ __launch_bounds__(128) void k_scanB(const int* __restrict__ bsum, int nb, int* __restrict__ boff){
  __shared__ int sd[128];
  int t = threadIdx.x;
  int v = (t < nb) ? bsum[t] : 0;
  sd[t] = v; __syncthreads();
  for (int off = 1; off < 128; off <<= 1){
    int a = sd[t];
    int u = (t >= off) ? sd[t - off] : 0;
    __syncthreads();
    sd[t] = a + u;
    __syncthreads();
  }
  if (t < nb) boff[t] = sd[t] - v;
}

__global__ __launch_bounds__(256) void k_scanC(const int* __restrict__ degi, int N,
                                               const int* __restrict__ boff,
                                               int* __restrict__ offs, int* __restrict__ cur){
  __shared__ int sd[256];
  int t = threadIdx.x;
  int base = blockIdx.x*1024 + t*4;
  int d0 = (base+0 < N) ? degi[base+0] : 0;
  int d1 = (base+1 < N) ? degi[base+1] : 0;
  int d2 = (base+2 < N) ? degi[base+2] : 0;
  int d3 = (base+3 < N) ? degi[base+3] : 0;
  int s = d0 + d1 + d2 + d3;
  sd[t] = s; __syncthreads();
  for (int off = 1; off < 256; off <<= 1){
    int a = sd[t];
    int u = (t >= off) ? sd[t - off] : 0;
    __syncthreads();
    sd[t] = a + u;
    __syncthreads();
  }
  int p0 = sd[t] - s + boff[blockIdx.x];
  int p1 = p0 + d0, p2 = p1 + d1, p3 = p2 + d2;
  if (base+0 < N){ offs[base+0] = p0; cur[base+0] = p0; }
  if (base+1 < N){ offs[base+1] = p1; cur[base+1] = p1; }
  if (base+2 < N){ offs[base+2] = p2; cur[base+2] = p2; }
  if (base+3 < N){ offs[base+3] = p3; cur[base+3] = p3; }
}

// ---- bucketed CSR build (replaces scattered-atomic k_fill) ----
// gcur[b] = csr segment base for bucket b (= offs[b*npb])
__global__ __launch_bounds__(256) void k_binit(const int* __restrict__ offs, int* __restrict__ gcur,
                                               int nbuck, int npb){
  int b = blockIdx.x*256 + threadIdx.x;
  if (b < nbuck) gcur[b] = offs[b*npb];
}

// Pass A: partition edges into buckets of npb nodes; pack (r<<shift)|loc.
__global__ __launch_bounds__(256) void k_bucket(const int* __restrict__ ei, const int* __restrict__ flag,
                                                int E, int nbuck, int shift,
                                                int* __restrict__ gcur, int* __restrict__ ebuf, int blkE){
  __shared__ int lh[2048];
  int t = threadIdx.x;
  int is64 = flag[0];
  for (int i = t; i < nbuck; i += 256) lh[i] = 0;
  __syncthreads();
  int e0 = blockIdx.x * blkE;
  int e1 = min(e0 + blkE, E);
  for (int e = e0 + t; e < e1; e += 256){
    int c = is64 ? ei[2*(E+e)] : ei[E+e];
    atomicAdd(&lh[c >> shift], 1);
  }
  __syncthreads();
  for (int i = t; i < nbuck; i += 256){
    int cnt = lh[i];
    lh[i] = cnt ? atomicAdd(&gcur[i], cnt) : 0;   // lh becomes global cursor base
  }
  __syncthreads();
  int mask = (1 << shift) - 1;
  for (int e = e0 + t; e < e1; e += 256){
    int r, c;
    if (is64){ r = ei[2*e]; c = ei[2*(E+e)]; }
    else     { r = ei[e];   c = ei[E+e];     }
    int b = c >> shift;
    int p = atomicAdd(&lh[b], 1);
    ebuf[p] = (r << shift) | (c & mask);
  }
}

// Pass B: per-bucket counting sort in LDS, coalesced csr write.
__global__ __launch_bounds__(256) void k_bsort(const int* __restrict__ ebuf, const int* __restrict__ offs,
                                               int* __restrict__ curp, int* __restrict__ csr,
                                               int N, int E, int npb, int shift){
  __shared__ int lcur[2048];
  __shared__ int lbuf[8192];
  int b = blockIdx.x;
  int n0 = b * npb;
  int n1 = min(n0 + npb, N);
  int s0 = offs[n0];
  int s1 = (n1 < N) ? offs[n1] : E;
  int size = s1 - s0;
  if (size <= 0) return;
  int t = threadIdx.x;
  int mask = npb - 1;
  if (size <= 8192){
    for (int i = t; i < n1 - n0; i += 256) lcur[i] = offs[n0 + i] - s0;
    __syncthreads();
    for (int k = t; k < size; k += 256){
      int v = ebuf[s0 + k];
      int p = atomicAdd(&lcur[v & mask], 1);
      lbuf[p] = v >> shift;
    }
    __syncthreads();
    for (int k = t; k < size; k += 256) csr[s0 + k] = lbuf[k];
  } else {
    // fallback for oversized buckets (adversarial input) — still correct
    for (int k = t; k < size; k += 256){
      int v = ebuf[s0 + k];
      int p = atomicAdd(&curp[n0 + (v & mask)], 1);
      csr[p] = v >> shift;
    }
  }
}

// ---- hs1 = dis * (x @ W1); BM=256 rows/block, BK=32, thread tile 4x4 ----
__global__ __launch_bounds__(256) void k_gemm1(const float* __restrict__ x, const float* __restrict__ W1,
                                               const float* __restrict__ dis, float* __restrict__ hs1, int N){
  __shared__ float xs[256*36];     // pad 32->36 (16B aligned, 2-way max conflict)
  __shared__ float wc[32*16];
  int t  = threadIdx.x;
  int R0 = blockIdx.x*256;
  int lr = t >> 3;                 // 0..31 (load row group)
  int lc = (t & 7) * 4;            // 0..28 (load col within 32-chunk)
  int rt = t >> 2;                 // 0..63 compute row group (rows rt*4+m)
  int jq = t & 3;                  // col quad (cols jq*4..+3)

  float4 acc0 = make_float4(0,0,0,0), acc1 = acc0, acc2 = acc0, acc3 = acc0;

  for (int kc = 0; kc < NF; kc += 32){
    #pragma unroll
    for (int li = 0; li < 8; ++li){
      int row = lr + li*32;
      int gr  = R0 + row;
      int grc = (gr < N) ? gr : 0;
      float4 v = *(const float4*)(x + (size_t)grc*NF + kc + lc);
      *(float4*)(xs + row*36 + lc) = v;
    }
    wc[t]       = W1[kc*16 + t];
    wc[t + 256] = W1[kc*16 + t + 256];
    __syncthreads();

    #pragma unroll
    for (int k0 = 0; k0 < 32; k0 += 4){
      float4 xr0 = *(const float4*)(xs + (rt*4+0)*36 + k0);
      float4 xr1 = *(const float4*)(xs + (rt*4+1)*36 + k0);
      float4 xr2 = *(const float4*)(xs + (rt*4+2)*36 + k0);
      float4 xr3 = *(const float4*)(xs + (rt*4+3)*36 + k0);
      float4 w0  = *(const float4*)(wc + (k0+0)*16 + jq*4);
      float4 w1  = *(const float4*)(wc + (k0+1)*16 + jq*4);
      float4 w2  = *(const float4*)(wc + (k0+2)*16 + jq*4);
      float4 w3  = *(const float4*)(wc + (k0+3)*16 + jq*4);
      acc0 = f4fma(acc0, xr0.x, w0); acc0 = f4fma(acc0, xr0.y, w1); acc0 = f4fma(acc0, xr0.z, w2); acc0 = f4fma(acc0, xr0.w, w3);
      acc1 = f4fma(acc1, xr1.x, w0); acc1 = f4fma(acc1, xr1.y, w1); acc1 = f4fma(acc1, xr1.z, w2); acc1 = f4fma(acc1, xr1.w, w3);
      acc2 = f4fma(acc2, xr2.x, w0); acc2 = f4fma(acc2, xr2.y, w1); acc2 = f4fma(acc2, xr2.z, w2); acc2 = f4fma(acc2, xr2.w, w3);
      acc3 = f4fma(acc3, xr3.x, w0); acc3 = f4fma(acc3, xr3.y, w1); acc3 = f4fma(acc3, xr3.z, w2); acc3 = f4fma(acc3, xr3.w, w3);
    }
    __syncthreads();
  }

  #pragma unroll
  for (int m = 0; m < 4; ++m){
    int gr = R0 + rt*4 + m;
    if (gr < N){
      float d = dis[gr];
      float4 a = (m==0)?acc0:(m==1)?acc1:(m==2)?acc2:acc3;
      float4 o = make_float4(a.x*d, a.y*d, a.z*d, a.w*d);
      *(float4*)(hs1 + (size_t)gr*16 + jq*4) = o;
    }
  }
}

// ---- layer1 aggregate + bias/ReLU + layer2 transform: hs2 = dis*(relu(dis*agg+b1) @ W2)
__global__ __launch_bounds__(256) void k_agg1(const float* __restrict__ hs1, const int* __restrict__ offs,
                                              const int* __restrict__ degi, const int* __restrict__ csr,
                                              const float* __restrict__ dis, const float* __restrict__ b1,
                                              const float* __restrict__ W2, float* __restrict__ hs2, int N){
  __shared__ float sW[112];
  __shared__ float sb[16];
  int t = threadIdx.x;
  if (t < 112) sW[t] = W2[t];
  if (t < 16)  sb[t] = b1[t];
  __syncthreads();

  int g = blockIdx.x*256 + t;
  int n = g >> 1, q = g & 1;
  if (n >= N) return;

  const float4* h4 = (const float4*)hs1;
  size_t base = (size_t)n*4 + q*2;
  float4 a0 = h4[base], a1 = h4[base+1];          // self-loop init
  int st = offs[n], cnt = degi[n];
  for (int i = 0; i < cnt; ++i){
    int s = csr[st + i];
    size_t sb4 = (size_t)s*4 + q*2;
    a0 = f4add(a0, h4[sb4]);
    a1 = f4add(a1, h4[sb4+1]);
  }
  float d = dis[n];
  float h[8];
  h[0] = fmaxf(fmaf(d, a0.x, sb[q*8+0]), 0.f);
  h[1] = fmaxf(fmaf(d, a0.y, sb[q*8+1]), 0.f);
  h[2] = fmaxf(fmaf(d, a0.z, sb[q*8+2]), 0.f);
  h[3] = fmaxf(fmaf(d, a0.w, sb[q*8+3]), 0.f);
  h[4] = fmaxf(fmaf(d, a1.x, sb[q*8+4]), 0.f);
  h[5] = fmaxf(fmaf(d, a1.y, sb[q*8+5]), 0.f);
  h[6] = fmaxf(fmaf(d, a1.z, sb[q*8+6]), 0.f);
  h[7] = fmaxf(fmaf(d, a1.w, sb[q*8+7]), 0.f);

  float acc[7] = {0,0,0,0,0,0,0};
  #pragma unroll
  for (int jj = 0; jj < 8; ++jj){
    int j = q*8 + jj;
    #pragma unroll
    for (int c = 0; c < 7; ++c) acc[c] = fmaf(h[jj], sW[j*7 + c], acc[c]);
  }
  #pragma unroll
  for (int c = 0; c < 7; ++c) acc[c] += __shfl_xor(acc[c], 1);

  if (q == 0){
    float4 o = make_float4(acc[0]*d, acc[1]*d, acc[2]*d, acc[3]*d);
    *(float4*)(hs2 + (size_t)n*8) = o;
  } else {
    float4 o = make_float4(acc[4]*d, acc[5]*d, acc[6]*d, 0.f);
    *(float4*)(hs2 + (size_t)n*8 + 4) = o;
  }
}

// ---- layer2 aggregate + bias -> out. 2 threads/node
__global__ __launch_bounds__(256) void k_agg2(const float* __restrict__ hs2, const int* __restrict__ offs,
                                              const int* __restrict__ degi, const int* __restrict__ csr,
                                              const float* __restrict__ dis, const float* __restrict__ b2,
                                              float* __restrict__ out, int N){
  int g = blockIdx.x*256 + threadIdx.x;
  int n = g >> 1, q = g & 1;
  if (n >= N) return;
  const float4* h4 = (const float4*)hs2;
  float4 a = h4[(size_t)n*2 + q];                 // self-loop init
  int st = offs[n], cnt = degi[n];
  for (int i = 0; i < cnt; ++i){
    int s = csr[st + i];
    a = f4add(a, h4[(size_t)s*2 + q]);
  }
  float d = dis[n];
  float* o = out + (size_t)n*7 + q*4;
  if (q == 0){
    o[0] = fmaf(d, a.x, b2[0]);
    o[1] = fmaf(d, a.y, b2[1]);
    o[2] = fmaf(d, a.z, b2[2]);
    o[3] = fmaf(d, a.w, b2[3]);
  } else {
    o[0] = fmaf(d, a.x, b2[4]);
    o[1] = fmaf(d, a.y, b2[5]);
    o[2] = fmaf(d, a.z, b2[6]);
  }
}

extern "C" void kernel_launch(void* const* d_in, const int* in_sizes, int n_in,
                              void* d_out, int out_size, void* d_ws, size_t ws_size,
                              hipStream_t stream){
  const float* x  = (const float*)d_in[0];
  const int*   ei = (const int*)d_in[1];
  const float* W1 = (const float*)d_in[2];
  const float* b1 = (const float*)d_in[3];
  const float* W2 = (const float*)d_in[4];
  const float* b2 = (const float*)d_in[5];
  float* out = (float*)d_out;

  const int N = in_sizes[0] / NF;      // 100000
  const int E = in_sizes[1] / 2;       // 3200000
  const int nb = (N + 1023) / 1024;    // scan blocks (98, must be <=128)

  // bucket geometry: npb = power-of-2 nodes/bucket, nbuck <= 2048
  int shift = 7;
  while (((N + (1 << shift) - 1) >> shift) > 2048) ++shift;
  const int npb   = 1 << shift;
  const int nbuck = (N + npb - 1) >> shift;
  const int blkE  = 16384;
  const int nblkB = (E + blkE - 1) / blkE;

  // ws carve-up (256B aligned)
  char* w = (char*)d_ws;
  size_t cur = 0;
  auto alloc = [&](size_t bytes)->char*{ char* p = w + cur; cur += (bytes + 255) & ~(size_t)255; return p; };
  int*   flag = (int*)  alloc(256);
  int*   degi = (int*)  alloc((size_t)N*4);
  float* dis  = (float*)alloc((size_t)N*4);
  int*   offs = (int*)  alloc((size_t)N*4);
  int*   curp = (int*)  alloc((size_t)N*4);
  int*   bsum = (int*)  alloc((size_t)nb*4);
  int*   boff = (int*)  alloc((size_t)nb*4);
  int*   gcur = (int*)  alloc((size_t)nbuck*4);
  int*   ebuf = (int*)  alloc((size_t)E*4);
  int*   csr  = (int*)  alloc((size_t)E*4);
  float* hs1  = (float*)alloc((size_t)N*16*4);
  float* hs2  = (float*)alloc((size_t)N*8*4);
  (void)ws_size; (void)n_in; (void)out_size;

  int gN  = (N + 255) / 256;
  int gE  = (E + 255) / 256;
  int g2N = (2*N + 255) / 256;
  int gB  = (nbuck + 255) / 256;

  k_detect<<<1, 256, 0, stream>>>(ei, flag);
  k_zero  <<<gN, 256, 0, stream>>>(degi, N);
  k_hist  <<<gE, 256, 0, stream>>>(ei, flag, E, degi);
  k_dis   <<<gN, 256, 0, stream>>>(degi, dis, N);
  k_scanA <<<nb, 256, 0, stream>>>(degi, N, bsum);
  k_scanB <<<1, 128, 0, stream>>>(bsum, nb, boff);
  k_scanC <<<nb, 256, 0, stream>>>(degi, N, boff, offs, curp);
  k_binit <<<gB, 256, 0, stream>>>(offs, gcur, nbuck, npb);
  k_bucket<<<nblkB, 256, 0, stream>>>(ei, flag, E, nbuck, shift, gcur, ebuf, blkE);
  k_bsort <<<nbuck, 256, 0, stream>>>(ebuf, offs, curp, csr, N, E, npb, shift);
  k_gemm1 <<<gN, 256, 0, stream>>>(x, W1, dis, hs1, N);
  k_agg1  <<<g2N, 256, 0, stream>>>(hs1, offs, degi, csr, dis, b1, W2, hs2, N);
  k_agg2  <<<g2N, 256, 0, stream>>>(hs2, offs, degi, csr, dis, b2, out, N);
}

// Round 3
// 265.867 us; speedup vs baseline: 2.0826x; 1.4169x over previous
//
#include <hip/hip_runtime.h>

#define NF   512
#define HIDD 16

__device__ inline float4 f4add(float4 a, float4 b){
  return make_float4(a.x+b.x, a.y+b.y, a.z+b.z, a.w+b.w);
}
__device__ inline float4 f4fma(float4 a, float s, float4 b){
  return make_float4(fmaf(s,b.x,a.x), fmaf(s,b.y,a.y), fmaf(s,b.z,a.z), fmaf(s,b.w,a.w));
}

// ---- dtype probe: int64 edge_index has all odd 32-bit words == 0 ----
__global__ __launch_bounds__(256) void k_detect(const int* __restrict__ ei, int* __restrict__ flag){
  __shared__ int any;
  if (threadIdx.x == 0) any = 0;
  __syncthreads();
  int found = 0;
  for (int i = 1 + 2*(int)threadIdx.x; i < 8192; i += 512) found |= (ei[i] != 0);
  if (found) any = 1;      // benign race, all write 1
  __syncthreads();
  if (threadIdx.x == 0) flag[0] = any ? 0 : 1;   // 1 => int64 layout
}

__global__ __launch_bounds__(256) void k_zb(int* __restrict__ p, int n){
  int i = blockIdx.x*256 + threadIdx.x;
  if (i < n) p[i] = 0;
}

// ---- Pass 0: bucket-count histogram (LDS-local, 1 global atomic per block x bucket) ----
__global__ __launch_bounds__(256) void k_bcount(const int* __restrict__ ei, const int* __restrict__ flag,
                                                int E, int nbuck, int shift,
                                                int* __restrict__ bcnt, int blkE){
  __shared__ int lh[2048];
  int t = threadIdx.x;
  int is64 = flag[0];
  for (int i = t; i < nbuck; i += 256) lh[i] = 0;
  __syncthreads();
  int e0 = blockIdx.x * blkE;
  int e1 = min(e0 + blkE, E);
  for (int e = e0 + t; e < e1; e += 256){
    int c = is64 ? ei[2*(E+e)] : ei[E+e];
    atomicAdd(&lh[c >> shift], 1);
  }
  __syncthreads();
  for (int i = t; i < nbuck; i += 256){
    int cnt = lh[i];
    if (cnt) atomicAdd(&bcnt[i], cnt);
  }
}

// ---- exclusive scan of bucket counts (single block) -> ebase, gcur ----
__global__ __launch_bounds__(256) void k_bscan(const int* __restrict__ bcnt, int nbuck,
                                               int* __restrict__ ebase, int* __restrict__ gcur){
  __shared__ int part[256];
  int t = threadIdx.x;
  int per = (nbuck + 255) >> 8;   // <= 8 since nbuck <= 2048
  int myv[8];
  int s = 0;
  #pragma unroll
  for (int j = 0; j < 8; ++j){
    int i = t*per + j;
    int v = (j < per && i < nbuck) ? bcnt[i] : 0;
    myv[j] = v; s += v;
  }
  part[t] = s; __syncthreads();
  for (int off = 1; off < 256; off <<= 1){
    int a = part[t];
    int u = (t >= off) ? part[t-off] : 0;
    __syncthreads();
    part[t] = a + u;
    __syncthreads();
  }
  int run = part[t] - s;
  #pragma unroll
  for (int j = 0; j < 8; ++j){
    int i = t*per + j;
    if (j < per && i < nbuck){
      ebase[i] = run; gcur[i] = run;
      run += myv[j];
    }
  }
  if (t == 255) ebase[nbuck] = run;   // == E
}

// ---- Pass A: partition edges into buckets of npb nodes; pack (r<<shift)|loc ----
__global__ __launch_bounds__(256) void k_bucket(const int* __restrict__ ei, const int* __restrict__ flag,
                                                int E, int nbuck, int shift,
                                                int* __restrict__ gcur, int* __restrict__ ebuf, int blkE){
  __shared__ int lh[2048];
  int t = threadIdx.x;
  int is64 = flag[0];
  for (int i = t; i < nbuck; i += 256) lh[i] = 0;
  __syncthreads();
  int e0 = blockIdx.x * blkE;
  int e1 = min(e0 + blkE, E);
  for (int e = e0 + t; e < e1; e += 256){
    int c = is64 ? ei[2*(E+e)] : ei[E+e];
    atomicAdd(&lh[c >> shift], 1);
  }
  __syncthreads();
  for (int i = t; i < nbuck; i += 256){
    int cnt = lh[i];
    lh[i] = cnt ? atomicAdd(&gcur[i], cnt) : 0;   // lh becomes global cursor base
  }
  __syncthreads();
  int mask = (1 << shift) - 1;
  for (int e = e0 + t; e < e1; e += 256){
    int r, c;
    if (is64){ r = ei[2*e]; c = ei[2*(E+e)]; }
    else     { r = ei[e];   c = ei[E+e];     }
    int b = c >> shift;
    int p = atomicAdd(&lh[b], 1);
    ebuf[p] = (r << shift) | (c & mask);
  }
}

// ---- Pass B: per-bucket counting sort in LDS; also emits degi/dis/offs (coalesced) ----
__global__ __launch_bounds__(256) void k_bsort(const int* __restrict__ ebuf, const int* __restrict__ ebase,
                                               int* __restrict__ degi, float* __restrict__ dis,
                                               int* __restrict__ offs, int* __restrict__ csr,
                                               int N, int npb, int shift){
  __shared__ int lcnt[2048];
  __shared__ int lpref[2048];
  __shared__ int part[256];
  __shared__ int lbuf[8192];
  int b = blockIdx.x;
  int n0 = b * npb;
  int n1 = min(n0 + npb, N);
  int nn = n1 - n0;
  int s0 = ebase[b];
  int s1 = ebase[b+1];
  int size = s1 - s0;
  int t = threadIdx.x;
  int mask = npb - 1;

  for (int i = t; i < nn; i += 256) lcnt[i] = 0;
  __syncthreads();
  for (int k = t; k < size; k += 256) atomicAdd(&lcnt[ebuf[s0 + k] & mask], 1);
  __syncthreads();

  // emit deg + dis (coalesced)
  for (int i = t; i < nn; i += 256){
    int c = lcnt[i];
    degi[n0 + i] = c;
    dis[n0 + i]  = rsqrtf((float)(c + 1));
  }

  // exclusive scan of lcnt -> lpref; emit offs
  int per = (nn + 255) >> 8;   // <= 8
  int myv[8];
  int s = 0;
  #pragma unroll
  for (int j = 0; j < 8; ++j){
    int i = t*per + j;
    int v = (j < per && i < nn) ? lcnt[i] : 0;
    myv[j] = v; s += v;
  }
  part[t] = s; __syncthreads();
  for (int off = 1; off < 256; off <<= 1){
    int a = part[t];
    int u = (t >= off) ? part[t-off] : 0;
    __syncthreads();
    part[t] = a + u;
    __syncthreads();
  }
  int run = part[t] - s;
  #pragma unroll
  for (int j = 0; j < 8; ++j){
    int i = t*per + j;
    if (j < per && i < nn){
      lpref[i] = run;
      offs[n0 + i] = s0 + run;
      run += myv[j];
    }
  }
  __syncthreads();

  // scatter rows by node (LDS cursors); stage in LDS when it fits
  if (size <= 8192){
    for (int k = t; k < size; k += 256){
      int v = ebuf[s0 + k];
      int p = atomicAdd(&lpref[v & mask], 1);
      lbuf[p] = v >> shift;
    }
    __syncthreads();
    for (int k = t; k < size; k += 256) csr[s0 + k] = lbuf[k];
  } else {
    for (int k = t; k < size; k += 256){
      int v = ebuf[s0 + k];
      int p = atomicAdd(&lpref[v & mask], 1);
      csr[s0 + p] = v >> shift;
    }
  }
}

// ---- hs1 = dis * (x @ W1); BM=256 rows/block, BK=32, thread tile 4x4 ----
__global__ __launch_bounds__(256) void k_gemm1(const float* __restrict__ x, const float* __restrict__ W1,
                                               const float* __restrict__ dis, float* __restrict__ hs1, int N){
  __shared__ float xs[256*36];     // pad 32->36 (16B aligned, 2-way max conflict)
  __shared__ float wc[32*16];
  int t  = threadIdx.x;
  int R0 = blockIdx.x*256;
  int lr = t >> 3;                 // 0..31 (load row group)
  int lc = (t & 7) * 4;            // 0..28 (load col within 32-chunk)
  int rt = t >> 2;                 // 0..63 compute row group (rows rt*4+m)
  int jq = t & 3;                  // col quad (cols jq*4..+3)

  float4 acc0 = make_float4(0,0,0,0), acc1 = acc0, acc2 = acc0, acc3 = acc0;

  for (int kc = 0; kc < NF; kc += 32){
    #pragma unroll
    for (int li = 0; li < 8; ++li){
      int row = lr + li*32;
      int gr  = R0 + row;
      int grc = (gr < N) ? gr : 0;
      float4 v = *(const float4*)(x + (size_t)grc*NF + kc + lc);
      *(float4*)(xs + row*36 + lc) = v;
    }
    wc[t]       = W1[kc*16 + t];
    wc[t + 256] = W1[kc*16 + t + 256];
    __syncthreads();

    #pragma unroll
    for (int k0 = 0; k0 < 32; k0 += 4){
      float4 xr0 = *(const float4*)(xs + (rt*4+0)*36 + k0);
      float4 xr1 = *(const float4*)(xs + (rt*4+1)*36 + k0);
      float4 xr2 = *(const float4*)(xs + (rt*4+2)*36 + k0);
      float4 xr3 = *(const float4*)(xs + (rt*4+3)*36 + k0);
      float4 w0  = *(const float4*)(wc + (k0+0)*16 + jq*4);
      float4 w1  = *(const float4*)(wc + (k0+1)*16 + jq*4);
      float4 w2  = *(const float4*)(wc + (k0+2)*16 + jq*4);
      float4 w3  = *(const float4*)(wc + (k0+3)*16 + jq*4);
      acc0 = f4fma(acc0, xr0.x, w0); acc0 = f4fma(acc0, xr0.y, w1); acc0 = f4fma(acc0, xr0.z, w2); acc0 = f4fma(acc0, xr0.w, w3);
      acc1 = f4fma(acc1, xr1.x, w0); acc1 = f4fma(acc1, xr1.y, w1); acc1 = f4fma(acc1, xr1.z, w2); acc1 = f4fma(acc1, xr1.w, w3);
      acc2 = f4fma(acc2, xr2.x, w0); acc2 = f4fma(acc2, xr2.y, w1); acc2 = f4fma(acc2, xr2.z, w2); acc2 = f4fma(acc2, xr2.w, w3);
      acc3 = f4fma(acc3, xr3.x, w0); acc3 = f4fma(acc3, xr3.y, w1); acc3 = f4fma(acc3, xr3.z, w2); acc3 = f4fma(acc3, xr3.w, w3);
    }
    __syncthreads();
  }

  #pragma unroll
  for (int m = 0; m < 4; ++m){
    int gr = R0 + rt*4 + m;
    if (gr < N){
      float d = dis[gr];
      float4 a = (m==0)?acc0:(m==1)?acc1:(m==2)?acc2:acc3;
      float4 o = make_float4(a.x*d, a.y*d, a.z*d, a.w*d);
      *(float4*)(hs1 + (size_t)gr*16 + jq*4) = o;
    }
  }
}

// ---- layer1 aggregate + bias/ReLU + layer2 transform: hs2 = dis*(relu(dis*agg+b1) @ W2)
__global__ __launch_bounds__(256) void k_agg1(const float* __restrict__ hs1, const int* __restrict__ offs,
                                              const int* __restrict__ degi, const int* __restrict__ csr,
                                              const float* __restrict__ dis, const float* __restrict__ b1,
                                              const float* __restrict__ W2, float* __restrict__ hs2, int N){
  __shared__ float sW[112];
  __shared__ float sb[16];
  int t = threadIdx.x;
  if (t < 112) sW[t] = W2[t];
  if (t < 16)  sb[t] = b1[t];
  __syncthreads();

  int g = blockIdx.x*256 + t;
  int n = g >> 1, q = g & 1;
  if (n >= N) return;

  const float4* h4 = (const float4*)hs1;
  size_t base = (size_t)n*4 + q*2;
  float4 a0 = h4[base], a1 = h4[base+1];          // self-loop init
  int st = offs[n], cnt = degi[n];
  for (int i = 0; i < cnt; ++i){
    int s = csr[st + i];
    size_t sb4 = (size_t)s*4 + q*2;
    a0 = f4add(a0, h4[sb4]);
    a1 = f4add(a1, h4[sb4+1]);
  }
  float d = dis[n];
  float h[8];
  h[0] = fmaxf(fmaf(d, a0.x, sb[q*8+0]), 0.f);
  h[1] = fmaxf(fmaf(d, a0.y, sb[q*8+1]), 0.f);
  h[2] = fmaxf(fmaf(d, a0.z, sb[q*8+2]), 0.f);
  h[3] = fmaxf(fmaf(d, a0.w, sb[q*8+3]), 0.f);
  h[4] = fmaxf(fmaf(d, a1.x, sb[q*8+4]), 0.f);
  h[5] = fmaxf(fmaf(d, a1.y, sb[q*8+5]), 0.f);
  h[6] = fmaxf(fmaf(d, a1.z, sb[q*8+6]), 0.f);
  h[7] = fmaxf(fmaf(d, a1.w, sb[q*8+7]), 0.f);

  float acc[7] = {0,0,0,0,0,0,0};
  #pragma unroll
  for (int jj = 0; jj < 8; ++jj){
    int j = q*8 + jj;
    #pragma unroll
    for (int c = 0; c < 7; ++c) acc[c] = fmaf(h[jj], sW[j*7 + c], acc[c]);
  }
  #pragma unroll
  for (int c = 0; c < 7; ++c) acc[c] += __shfl_xor(acc[c], 1);

  if (q == 0){
    float4 o = make_float4(acc[0]*d, acc[1]*d, acc[2]*d, acc[3]*d);
    *(float4*)(hs2 + (size_t)n*8) = o;
  } else {
    float4 o = make_float4(acc[4]*d, acc[5]*d, acc[6]*d, 0.f);
    *(float4*)(hs2 + (size_t)n*8 + 4) = o;
  }
}

// ---- layer2 aggregate + bias -> out. 2 threads/node
__global__ __launch_bounds__(256) void k_agg2(const float* __restrict__ hs2, const int* __restrict__ offs,
                                              const int* __restrict__ degi, const int* __restrict__ csr,
                                              const float* __restrict__ dis, const float* __restrict__ b2,
                                              float* __restrict__ out, int N){
  int g = blockIdx.x*256 + threadIdx.x;
  int n = g >> 1, q = g & 1;
  if (n >= N) return;
  const float4* h4 = (const float4*)hs2;
  float4 a = h4[(size_t)n*2 + q];                 // self-loop init
  int st = offs[n], cnt = degi[n];
  for (int i = 0; i < cnt; ++i){
    int s = csr[st + i];
    a = f4add(a, h4[(size_t)s*2 + q]);
  }
  float d = dis[n];
  float* o = out + (size_t)n*7 + q*4;
  if (q == 0){
    o[0] = fmaf(d, a.x, b2[0]);
    o[1] = fmaf(d, a.y, b2[1]);
    o[2] = fmaf(d, a.z, b2[2]);
    o[3] = fmaf(d, a.w, b2[3]);
  } else {
    o[0] = fmaf(d, a.x, b2[4]);
    o[1] = fmaf(d, a.y, b2[5]);
    o[2] = fmaf(d, a.z, b2[6]);
  }
}

extern "C" void kernel_launch(void* const* d_in, const int* in_sizes, int n_in,
                              void* d_out, int out_size, void* d_ws, size_t ws_size,
                              hipStream_t stream){
  const float* x  = (const float*)d_in[0];
  const int*   ei = (const int*)d_in[1];
  const float* W1 = (const float*)d_in[2];
  const float* b1 = (const float*)d_in[3];
  const float* W2 = (const float*)d_in[4];
  const float* b2 = (const float*)d_in[5];
  float* out = (float*)d_out;

  const int N = in_sizes[0] / NF;      // 100000
  const int E = in_sizes[1] / 2;       // 3200000

  // bucket geometry: npb = power-of-2 nodes/bucket, nbuck <= 2048
  int shift = 7;
  while (((N + (1 << shift) - 1) >> shift) > 2048) ++shift;
  const int npb   = 1 << shift;
  const int nbuck = (N + npb - 1) >> shift;
  const int blkE  = 16384;
  const int nblkB = (E + blkE - 1) / blkE;

  // ws carve-up (256B aligned)
  char* w = (char*)d_ws;
  size_t cur = 0;
  auto alloc = [&](size_t bytes)->char*{ char* p = w + cur; cur += (bytes + 255) & ~(size_t)255; return p; };
  int*   flag  = (int*)  alloc(256);
  int*   bcnt  = (int*)  alloc((size_t)(nbuck+1)*4);
  int*   ebase = (int*)  alloc((size_t)(nbuck+1)*4);
  int*   gcur  = (int*)  alloc((size_t)nbuck*4);
  int*   degi  = (int*)  alloc((size_t)N*4);
  float* dis   = (float*)alloc((size_t)N*4);
  int*   offs  = (int*)  alloc((size_t)N*4);
  int*   ebuf  = (int*)  alloc((size_t)E*4);
  int*   csr   = (int*)  alloc((size_t)E*4);
  float* hs1   = (float*)alloc((size_t)N*16*4);
  float* hs2   = (float*)alloc((size_t)N*8*4);
  (void)ws_size; (void)n_in; (void)out_size;

  int gN  = (N + 255) / 256;
  int g2N = (2*N + 255) / 256;
  int gB  = (nbuck + 255) / 256;

  k_detect<<<1, 256, 0, stream>>>(ei, flag);
  k_zb    <<<gB, 256, 0, stream>>>(bcnt, nbuck);
  k_bcount<<<nblkB, 256, 0, stream>>>(ei, flag, E, nbuck, shift, bcnt, blkE);
  k_bscan <<<1, 256, 0, stream>>>(bcnt, nbuck, ebase, gcur);
  k_bucket<<<nblkB, 256, 0, stream>>>(ei, flag, E, nbuck, shift, gcur, ebuf, blkE);
  k_bsort <<<nbuck, 256, 0, stream>>>(ebuf, ebase, degi, dis, offs, csr, N, npb, shift);
  k_gemm1 <<<gN, 256, 0, stream>>>(x, W1, dis, hs1, N);
  k_agg1  <<<g2N, 256, 0, stream>>>(hs1, offs, degi, csr, dis, b1, W2, hs2, N);
  k_agg2  <<<g2N, 256, 0, stream>>>(hs2, offs, degi, csr, dis, b2, out, N);
}

// Round 4
// 248.622 us; speedup vs baseline: 2.2270x; 1.0694x over previous
//
#include <hip/hip_runtime.h>

#define NF   512
#define BLKE 8192

__device__ inline float4 f4add(float4 a, float4 b){
  return make_float4(a.x+b.x, a.y+b.y, a.z+b.z, a.w+b.w);
}
__device__ inline float4 f4fma(float4 a, float s, float4 b){
  return make_float4(fmaf(s,b.x,a.x), fmaf(s,b.y,a.y), fmaf(s,b.z,a.z), fmaf(s,b.w,a.w));
}

// ---- dtype probe: int64 edge_index has all odd 32-bit words == 0 ----
__global__ __launch_bounds__(256) void k_detect(const int* __restrict__ ei, int* __restrict__ flag){
  __shared__ int any;
  if (threadIdx.x == 0) any = 0;
  __syncthreads();
  int found = 0;
  for (int i = 1 + 2*(int)threadIdx.x; i < 8192; i += 512) found |= (ei[i] != 0);
  if (found) any = 1;      // benign race, all write 1
  __syncthreads();
  if (threadIdx.x == 0) flag[0] = any ? 0 : 1;   // 1 => int64 layout
}

// ---- Pass A: per-block LDS counting sort by bucket; coalesced flush to own region ----
// Emits cnt2d[blk][buck] and lpos2d[blk][buck] (run start within block region).
__global__ __launch_bounds__(256) void k_blocal(const int* __restrict__ ei, const int* __restrict__ flag,
                                                int E, int nbuck, int shift,
                                                int* __restrict__ ebuf, int* __restrict__ cnt2d,
                                                int* __restrict__ lpos2d){
  __shared__ int lh[2048];
  __shared__ int part[256];
  __shared__ int lbuf[BLKE];
  int t = threadIdx.x;
  int is64 = flag[0];
  int blk = blockIdx.x;
  int e0 = blk * BLKE;
  int e1 = min(e0 + BLKE, E);
  int cnt = e1 - e0;
  for (int i = t; i < nbuck; i += 256) lh[i] = 0;
  __syncthreads();
  for (int e = e0 + t; e < e1; e += 256){
    int c = is64 ? ei[2*(E+e)] : ei[E+e];
    atomicAdd(&lh[c >> shift], 1);
  }
  __syncthreads();
  // exclusive scan lh over nbuck; emit cnt2d/lpos2d; lh becomes cursor
  int per = (nbuck + 255) >> 8;   // <= 8
  int myv[8];
  int s = 0;
  #pragma unroll
  for (int j = 0; j < 8; ++j){
    int i = t*per + j;
    int v = (j < per && i < nbuck) ? lh[i] : 0;
    myv[j] = v; s += v;
  }
  part[t] = s; __syncthreads();
  for (int off = 1; off < 256; off <<= 1){
    int a = part[t];
    int u = (t >= off) ? part[t-off] : 0;
    __syncthreads();
    part[t] = a + u;
    __syncthreads();
  }
  int run = part[t] - s;
  #pragma unroll
  for (int j = 0; j < 8; ++j){
    int i = t*per + j;
    if (j < per && i < nbuck){
      cnt2d [(size_t)blk*nbuck + i] = myv[j];
      lpos2d[(size_t)blk*nbuck + i] = run;
      lh[i] = run;
      run += myv[j];
    }
  }
  __syncthreads();
  int mask = (1 << shift) - 1;
  for (int e = e0 + t; e < e1; e += 256){
    int r, c;
    if (is64){ r = ei[2*e]; c = ei[2*(E+e)]; }
    else     { r = ei[e];   c = ei[E+e];     }
    int b = c >> shift;
    int p = atomicAdd(&lh[b], 1);
    lbuf[p] = (r << shift) | (c & mask);
  }
  __syncthreads();
  for (int k = t; k < cnt; k += 256) ebuf[e0 + k] = lbuf[k];   // fully coalesced
}

// ---- per-bucket scan of cnt2d across blocks -> prefix (in place) + btot ----
__global__ __launch_bounds__(256) void k_cscan(int* __restrict__ cnt2d, int nblk, int nbuck,
                                               int* __restrict__ btot){
  __shared__ int part[256];
  int b = blockIdx.x;
  int t = threadIdx.x;
  int per = (nblk + 255) >> 8;   // <= 8 (nblk <= 2048)
  int myv[8];
  int s = 0;
  #pragma unroll
  for (int j = 0; j < 8; ++j){
    int i = t*per + j;
    int v = (j < per && i < nblk) ? cnt2d[(size_t)i*nbuck + b] : 0;
    myv[j] = v; s += v;
  }
  part[t] = s; __syncthreads();
  for (int off = 1; off < 256; off <<= 1){
    int a = part[t];
    int u = (t >= off) ? part[t-off] : 0;
    __syncthreads();
    part[t] = a + u;
    __syncthreads();
  }
  int run = part[t] - s;
  #pragma unroll
  for (int j = 0; j < 8; ++j){
    int i = t*per + j;
    if (j < per && i < nblk){
      cnt2d[(size_t)i*nbuck + b] = run;   // overwrite with exclusive prefix
      run += myv[j];
    }
  }
  if (t == 255) btot[b] = part[255];
}

// ---- exclusive scan of bucket totals -> ebase[0..nbuck] ----
__global__ __launch_bounds__(256) void k_bscan(const int* __restrict__ btot, int nbuck,
                                               int* __restrict__ ebase){
  __shared__ int part[256];
  int t = threadIdx.x;
  int per = (nbuck + 255) >> 8;
  int myv[8];
  int s = 0;
  #pragma unroll
  for (int j = 0; j < 8; ++j){
    int i = t*per + j;
    int v = (j < per && i < nbuck) ? btot[i] : 0;
    myv[j] = v; s += v;
  }
  part[t] = s; __syncthreads();
  for (int off = 1; off < 256; off <<= 1){
    int a = part[t];
    int u = (t >= off) ? part[t-off] : 0;
    __syncthreads();
    part[t] = a + u;
    __syncthreads();
  }
  int run = part[t] - s;
  #pragma unroll
  for (int j = 0; j < 8; ++j){
    int i = t*per + j;
    if (j < per && i < nbuck){
      ebase[i] = run;
      run += myv[j];
    }
  }
  if (t == 255) ebase[nbuck] = part[255];   // == E
}

// ---- Pass B: per-bucket gather of segments + LDS node counting sort -> csr/degi/dis/offs ----
__global__ __launch_bounds__(256) void k_bsort(const int* __restrict__ ebuf, const int* __restrict__ segp2d,
                                               const int* __restrict__ lpos2d, const int* __restrict__ ebase,
                                               int* __restrict__ degi, float* __restrict__ dis,
                                               int* __restrict__ offs, int* __restrict__ csr,
                                               int N, int npb, int shift, int nblk, int nbuck){
  __shared__ int segp[2048];
  __shared__ int segs[2048];
  __shared__ int lcnt[2048];
  __shared__ int lpref[2048];
  __shared__ int part[256];
  __shared__ int lbuf[8192];
  int b = blockIdx.x;
  int t = threadIdx.x;
  int n0 = b * npb;
  int n1 = min(n0 + npb, N);
  int nn = n1 - n0;
  int s0 = ebase[b];
  int size = ebase[b+1] - s0;
  int mask = npb - 1;

  for (int i = t; i < nblk; i += 256){
    segp[i] = segp2d[(size_t)i*nbuck + b];
    segs[i] = lpos2d[(size_t)i*nbuck + b];
  }
  for (int i = t; i < nn; i += 256) lcnt[i] = 0;
  __syncthreads();

  bool staged = (size <= 8192);
  // pass 1: count (+ stage into LDS)
  for (int k = t; k < size; k += 256){
    int lo = 0, hi = nblk - 1;
    while (lo < hi){ int mid = (lo + hi + 1) >> 1; if (segp[mid] <= k) lo = mid; else hi = mid - 1; }
    int v = ebuf[lo*BLKE + segs[lo] + (k - segp[lo])];
    if (staged) lbuf[k] = v;
    atomicAdd(&lcnt[v & mask], 1);
  }
  __syncthreads();

  // emit degi/dis (coalesced) — also for empty buckets
  for (int i = t; i < nn; i += 256){
    int c = lcnt[i];
    degi[n0 + i] = c;
    dis[n0 + i]  = rsqrtf((float)(c + 1));
  }
  // exclusive scan lcnt -> lpref; emit offs
  int per = (nn + 255) >> 8;
  int myv[8];
  int s = 0;
  #pragma unroll
  for (int j = 0; j < 8; ++j){
    int i = t*per + j;
    int v = (j < per && i < nn) ? lcnt[i] : 0;
    myv[j] = v; s += v;
  }
  part[t] = s; __syncthreads();
  for (int off = 1; off < 256; off <<= 1){
    int a = part[t];
    int u = (t >= off) ? part[t-off] : 0;
    __syncthreads();
    part[t] = a + u;
    __syncthreads();
  }
  int run = part[t] - s;
  #pragma unroll
  for (int j = 0; j < 8; ++j){
    int i = t*per + j;
    if (j < per && i < nn){
      lpref[i] = run;
      offs[n0 + i] = s0 + run;
      run += myv[j];
    }
  }
  __syncthreads();

  // pass 2: scatter rows by node
  if (staged){
    for (int k = t; k < size; k += 256){
      int v = lbuf[k];
      int p = atomicAdd(&lpref[v & mask], 1);
      csr[s0 + p] = v >> shift;
    }
  } else {
    for (int k = t; k < size; k += 256){
      int lo = 0, hi = nblk - 1;
      while (lo < hi){ int mid = (lo + hi + 1) >> 1; if (segp[mid] <= k) lo = mid; else hi = mid - 1; }
      int v = ebuf[lo*BLKE + segs[lo] + (k - segp[lo])];
      int p = atomicAdd(&lpref[v & mask], 1);
      csr[s0 + p] = v >> shift;
    }
  }
}

// ---- hs1 = dis * (x @ W1); BM=128 rows/block, BK=32, thread tile 2x4 ----
__global__ __launch_bounds__(256) void k_gemm1(const float* __restrict__ x, const float* __restrict__ W1,
                                               const float* __restrict__ dis, float* __restrict__ hs1, int N){
  __shared__ float xs[128*36];     // pad 32->36
  __shared__ float wc[32*16];
  int t  = threadIdx.x;
  int R0 = blockIdx.x*128;
  int lr = t >> 3;                 // 0..31 (load row group)
  int lc = (t & 7) * 4;            // 0..28
  int rt = t >> 2;                 // 0..63 -> rows rt*2+{0,1}
  int jq = t & 3;                  // col quad

  float4 acc0 = make_float4(0,0,0,0), acc1 = acc0;

  for (int kc = 0; kc < NF; kc += 32){
    #pragma unroll
    for (int li = 0; li < 4; ++li){
      int row = lr + li*32;
      int gr  = R0 + row;
      int grc = (gr < N) ? gr : 0;
      float4 v = *(const float4*)(x + (size_t)grc*NF + kc + lc);
      *(float4*)(xs + row*36 + lc) = v;
    }
    wc[t]       = W1[kc*16 + t];
    wc[t + 256] = W1[kc*16 + t + 256];
    __syncthreads();

    #pragma unroll
    for (int k0 = 0; k0 < 32; k0 += 4){
      float4 xr0 = *(const float4*)(xs + (rt*2+0)*36 + k0);
      float4 xr1 = *(const float4*)(xs + (rt*2+1)*36 + k0);
      float4 w0  = *(const float4*)(wc + (k0+0)*16 + jq*4);
      float4 w1  = *(const float4*)(wc + (k0+1)*16 + jq*4);
      float4 w2  = *(const float4*)(wc + (k0+2)*16 + jq*4);
      float4 w3  = *(const float4*)(wc + (k0+3)*16 + jq*4);
      acc0 = f4fma(acc0, xr0.x, w0); acc0 = f4fma(acc0, xr0.y, w1); acc0 = f4fma(acc0, xr0.z, w2); acc0 = f4fma(acc0, xr0.w, w3);
      acc1 = f4fma(acc1, xr1.x, w0); acc1 = f4fma(acc1, xr1.y, w1); acc1 = f4fma(acc1, xr1.z, w2); acc1 = f4fma(acc1, xr1.w, w3);
    }
    __syncthreads();
  }

  #pragma unroll
  for (int m = 0; m < 2; ++m){
    int gr = R0 + rt*2 + m;
    if (gr < N){
      float d = dis[gr];
      float4 a = (m==0) ? acc0 : acc1;
      float4 o = make_float4(a.x*d, a.y*d, a.z*d, a.w*d);
      *(float4*)(hs1 + (size_t)gr*16 + jq*4) = o;
    }
  }
}

// ---- layer1 aggregate + bias/ReLU + layer2 transform: hs2 = dis*(relu(dis*agg+b1) @ W2)
__global__ __launch_bounds__(256) void k_agg1(const float* __restrict__ hs1, const int* __restrict__ offs,
                                              const int* __restrict__ degi, const int* __restrict__ csr,
                                              const float* __restrict__ dis, const float* __restrict__ b1,
                                              const float* __restrict__ W2, float* __restrict__ hs2, int N){
  __shared__ float sW[112];
  __shared__ float sb[16];
  int t = threadIdx.x;
  if (t < 112) sW[t] = W2[t];
  if (t < 16)  sb[t] = b1[t];
  __syncthreads();

  int g = blockIdx.x*256 + t;
  int n = g >> 1, q = g & 1;
  if (n >= N) return;

  const float4* h4 = (const float4*)hs1;
  size_t base = (size_t)n*4 + q*2;
  float4 a0 = h4[base], a1 = h4[base+1];          // self-loop init
  int st = offs[n], cnt = degi[n];
  for (int i = 0; i < cnt; ++i){
    int s = csr[st + i];
    size_t sb4 = (size_t)s*4 + q*2;
    a0 = f4add(a0, h4[sb4]);
    a1 = f4add(a1, h4[sb4+1]);
  }
  float d = dis[n];
  float h[8];
  h[0] = fmaxf(fmaf(d, a0.x, sb[q*8+0]), 0.f);
  h[1] = fmaxf(fmaf(d, a0.y, sb[q*8+1]), 0.f);
  h[2] = fmaxf(fmaf(d, a0.z, sb[q*8+2]), 0.f);
  h[3] = fmaxf(fmaf(d, a0.w, sb[q*8+3]), 0.f);
  h[4] = fmaxf(fmaf(d, a1.x, sb[q*8+4]), 0.f);
  h[5] = fmaxf(fmaf(d, a1.y, sb[q*8+5]), 0.f);
  h[6] = fmaxf(fmaf(d, a1.z, sb[q*8+6]), 0.f);
  h[7] = fmaxf(fmaf(d, a1.w, sb[q*8+7]), 0.f);

  float acc[7] = {0,0,0,0,0,0,0};
  #pragma unroll
  for (int jj = 0; jj < 8; ++jj){
    int j = q*8 + jj;
    #pragma unroll
    for (int c = 0; c < 7; ++c) acc[c] = fmaf(h[jj], sW[j*7 + c], acc[c]);
  }
  #pragma unroll
  for (int c = 0; c < 7; ++c) acc[c] += __shfl_xor(acc[c], 1);

  if (q == 0){
    float4 o = make_float4(acc[0]*d, acc[1]*d, acc[2]*d, acc[3]*d);
    *(float4*)(hs2 + (size_t)n*8) = o;
  } else {
    float4 o = make_float4(acc[4]*d, acc[5]*d, acc[6]*d, 0.f);
    *(float4*)(hs2 + (size_t)n*8 + 4) = o;
  }
}

// ---- layer2 aggregate + bias -> out. 2 threads/node
__global__ __launch_bounds__(256) void k_agg2(const float* __restrict__ hs2, const int* __restrict__ offs,
                                              const int* __restrict__ degi, const int* __restrict__ csr,
                                              const float* __restrict__ dis, const float* __restrict__ b2,
                                              float* __restrict__ out, int N){
  int g = blockIdx.x*256 + threadIdx.x;
  int n = g >> 1, q = g & 1;
  if (n >= N) return;
  const float4* h4 = (const float4*)hs2;
  float4 a = h4[(size_t)n*2 + q];                 // self-loop init
  int st = offs[n], cnt = degi[n];
  for (int i = 0; i < cnt; ++i){
    int s = csr[st + i];
    a = f4add(a, h4[(size_t)s*2 + q]);
  }
  float d = dis[n];
  float* o = out + (size_t)n*7 + q*4;
  if (q == 0){
    o[0] = fmaf(d, a.x, b2[0]);
    o[1] = fmaf(d, a.y, b2[1]);
    o[2] = fmaf(d, a.z, b2[2]);
    o[3] = fmaf(d, a.w, b2[3]);
  } else {
    o[0] = fmaf(d, a.x, b2[4]);
    o[1] = fmaf(d, a.y, b2[5]);
    o[2] = fmaf(d, a.z, b2[6]);
  }
}

extern "C" void kernel_launch(void* const* d_in, const int* in_sizes, int n_in,
                              void* d_out, int out_size, void* d_ws, size_t ws_size,
                              hipStream_t stream){
  const float* x  = (const float*)d_in[0];
  const int*   ei = (const int*)d_in[1];
  const float* W1 = (const float*)d_in[2];
  const float* b1 = (const float*)d_in[3];
  const float* W2 = (const float*)d_in[4];
  const float* b2 = (const float*)d_in[5];
  float* out = (float*)d_out;

  const int N = in_sizes[0] / NF;      // 100000
  const int E = in_sizes[1] / 2;       // 3200000

  // bucket geometry: npb = power-of-2 nodes/bucket, nbuck <= 2048
  int shift = 7;
  while (((N + (1 << shift) - 1) >> shift) > 2048) ++shift;
  const int npb   = 1 << shift;
  const int nbuck = (N + npb - 1) >> shift;
  const int nblk  = (E + BLKE - 1) / BLKE;   // must be <= 2048 (E <= 16.7M)

  // ws carve-up (256B aligned)
  char* w = (char*)d_ws;
  size_t cur = 0;
  auto alloc = [&](size_t bytes)->char*{ char* p = w + cur; cur += (bytes + 255) & ~(size_t)255; return p; };
  int*   flag   = (int*)  alloc(256);
  int*   cnt2d  = (int*)  alloc((size_t)nblk*nbuck*4);
  int*   lpos2d = (int*)  alloc((size_t)nblk*nbuck*4);
  int*   btot   = (int*)  alloc((size_t)(nbuck+1)*4);
  int*   ebase  = (int*)  alloc((size_t)(nbuck+1)*4);
  int*   degi   = (int*)  alloc((size_t)N*4);
  float* dis    = (float*)alloc((size_t)N*4);
  int*   offs   = (int*)  alloc((size_t)N*4);
  int*   ebuf   = (int*)  alloc((size_t)nblk*BLKE*4);
  int*   csr    = (int*)  alloc((size_t)E*4);
  float* hs1    = (float*)alloc((size_t)N*16*4);
  float* hs2    = (float*)alloc((size_t)N*8*4);
  (void)ws_size; (void)n_in; (void)out_size;

  int gM  = (N + 127) / 128;
  int g2N = (2*N + 255) / 256;

  k_detect<<<1, 256, 0, stream>>>(ei, flag);
  k_blocal<<<nblk, 256, 0, stream>>>(ei, flag, E, nbuck, shift, ebuf, cnt2d, lpos2d);
  k_cscan <<<nbuck, 256, 0, stream>>>(cnt2d, nblk, nbuck, btot);
  k_bscan <<<1, 256, 0, stream>>>(btot, nbuck, ebase);
  k_bsort <<<nbuck, 256, 0, stream>>>(ebuf, cnt2d, lpos2d, ebase, degi, dis, offs, csr,
                                      N, npb, shift, nblk, nbuck);
  k_gemm1 <<<gM, 256, 0, stream>>>(x, W1, dis, hs1, N);
  k_agg1  <<<g2N, 256, 0, stream>>>(hs1, offs, degi, csr, dis, b1, W2, hs2, N);
  k_agg2  <<<g2N, 256, 0, stream>>>(hs2, offs, degi, csr, dis, b2, out, N);
}

// Round 5
// 226.692 us; speedup vs baseline: 2.4425x; 1.0967x over previous
//
#include <hip/hip_runtime.h>

#define NF   512
#define BLKE 8192

__device__ inline float4 f4add(float4 a, float4 b){
  return make_float4(a.x+b.x, a.y+b.y, a.z+b.z, a.w+b.w);
}
__device__ inline float4 f4fma(float4 a, float s, float4 b){
  return make_float4(fmaf(s,b.x,a.x), fmaf(s,b.y,a.y), fmaf(s,b.z,a.z), fmaf(s,b.w,a.w));
}

// ---- dtype probe: int64 edge_index has all odd 32-bit words == 0 ----
__global__ __launch_bounds__(256) void k_detect(const int* __restrict__ ei, int* __restrict__ flag){
  __shared__ int any;
  if (threadIdx.x == 0) any = 0;
  __syncthreads();
  int found = 0;
  for (int i = 1 + 2*(int)threadIdx.x; i < 8192; i += 512) found |= (ei[i] != 0);
  if (found) any = 1;      // benign race, all write 1
  __syncthreads();
  if (threadIdx.x == 0) flag[0] = any ? 0 : 1;   // 1 => int64 layout
}

// ---- Pass A: per-block LDS counting sort by bucket; coalesced flush to own region ----
__global__ __launch_bounds__(256) void k_blocal(const int* __restrict__ ei, const int* __restrict__ flag,
                                                int E, int nbuck, int shift,
                                                int* __restrict__ ebuf, int* __restrict__ cnt2d,
                                                int* __restrict__ lpos2d){
  __shared__ int lh[2048];
  __shared__ int part[256];
  __shared__ int lbuf[BLKE];
  int t = threadIdx.x;
  int is64 = flag[0];
  int blk = blockIdx.x;
  int e0 = blk * BLKE;
  int e1 = min(e0 + BLKE, E);
  int cnt = e1 - e0;
  for (int i = t; i < nbuck; i += 256) lh[i] = 0;
  __syncthreads();
  for (int e = e0 + t; e < e1; e += 256){
    int c = is64 ? ei[2*(E+e)] : ei[E+e];
    atomicAdd(&lh[c >> shift], 1);
  }
  __syncthreads();
  // exclusive scan lh over nbuck; emit cnt2d/lpos2d; lh becomes cursor
  int per = (nbuck + 255) >> 8;   // <= 8
  int myv[8];
  int s = 0;
  #pragma unroll
  for (int j = 0; j < 8; ++j){
    int i = t*per + j;
    int v = (j < per && i < nbuck) ? lh[i] : 0;
    myv[j] = v; s += v;
  }
  part[t] = s; __syncthreads();
  for (int off = 1; off < 256; off <<= 1){
    int a = part[t];
    int u = (t >= off) ? part[t-off] : 0;
    __syncthreads();
    part[t] = a + u;
    __syncthreads();
  }
  int run = part[t] - s;
  #pragma unroll
  for (int j = 0; j < 8; ++j){
    int i = t*per + j;
    if (j < per && i < nbuck){
      cnt2d [(size_t)blk*nbuck + i] = myv[j];
      lpos2d[(size_t)blk*nbuck + i] = run;
      lh[i] = run;
      run += myv[j];
    }
  }
  __syncthreads();
  int mask = (1 << shift) - 1;
  for (int e = e0 + t; e < e1; e += 256){
    int r, c;
    if (is64){ r = ei[2*e]; c = ei[2*(E+e)]; }
    else     { r = ei[e];   c = ei[E+e];     }
    int b = c >> shift;
    int p = atomicAdd(&lh[b], 1);
    lbuf[p] = (r << shift) | (c & mask);
  }
  __syncthreads();
  for (int k = t; k < cnt; k += 256) ebuf[e0 + k] = lbuf[k];   // fully coalesced
}

// ---- per-bucket scan of cnt2d across blocks -> prefix (in place) + btot ----
__global__ __launch_bounds__(256) void k_cscan(int* __restrict__ cnt2d, int nblk, int nbuck,
                                               int* __restrict__ btot){
  __shared__ int part[256];
  int b = blockIdx.x;
  int t = threadIdx.x;
  int per = (nblk + 255) >> 8;   // <= 8
  int myv[8];
  int s = 0;
  #pragma unroll
  for (int j = 0; j < 8; ++j){
    int i = t*per + j;
    int v = (j < per && i < nblk) ? cnt2d[(size_t)i*nbuck + b] : 0;
    myv[j] = v; s += v;
  }
  part[t] = s; __syncthreads();
  for (int off = 1; off < 256; off <<= 1){
    int a = part[t];
    int u = (t >= off) ? part[t-off] : 0;
    __syncthreads();
    part[t] = a + u;
    __syncthreads();
  }
  int run = part[t] - s;
  #pragma unroll
  for (int j = 0; j < 8; ++j){
    int i = t*per + j;
    if (j < per && i < nblk){
      cnt2d[(size_t)i*nbuck + b] = run;   // overwrite with exclusive prefix (dest within bucket)
      run += myv[j];
    }
  }
  if (t == 255) btot[b] = part[255];
}

// ---- exclusive scan of bucket totals -> ebase[0..nbuck] ----
__global__ __launch_bounds__(256) void k_bscan(const int* __restrict__ btot, int nbuck,
                                               int* __restrict__ ebase){
  __shared__ int part[256];
  int t = threadIdx.x;
  int per = (nbuck + 255) >> 8;
  int myv[8];
  int s = 0;
  #pragma unroll
  for (int j = 0; j < 8; ++j){
    int i = t*per + j;
    int v = (j < per && i < nbuck) ? btot[i] : 0;
    myv[j] = v; s += v;
  }
  part[t] = s; __syncthreads();
  for (int off = 1; off < 256; off <<= 1){
    int a = part[t];
    int u = (t >= off) ? part[t-off] : 0;
    __syncthreads();
    part[t] = a + u;
    __syncthreads();
  }
  int run = part[t] - s;
  #pragma unroll
  for (int j = 0; j < 8; ++j){
    int i = t*per + j;
    if (j < per && i < nbuck){
      ebase[i] = run;
      run += myv[j];
    }
  }
  if (t == 255) ebase[nbuck] = part[255];   // == E
}

// ---- Pass B: per-bucket segment-march counting sort -> csr/degi/dis/offs (no binary search) ----
__global__ __launch_bounds__(256) void k_bsort(const int* __restrict__ ebuf, const int* __restrict__ segp2d,
                                               const int* __restrict__ lpos2d, const int* __restrict__ ebase,
                                               int* __restrict__ degi, float* __restrict__ dis,
                                               int* __restrict__ offs, int* __restrict__ csr,
                                               int N, int npb, int shift, int nblk, int nbuck){
  __shared__ int segp[2048];   // dest-prefix within bucket (cumulative counts over blocks)
  __shared__ int segs[2048];   // src start within each block's ebuf region
  __shared__ int lcnt[2048];   // per-node count -> then cursor
  __shared__ int part[256];
  int b = blockIdx.x;
  int t = threadIdx.x;
  int n0 = b * npb;
  int n1 = min(n0 + npb, N);
  int nn = n1 - n0;
  int s0 = ebase[b];
  int size = ebase[b+1] - s0;
  int mask = npb - 1;

  for (int i = t; i < nblk; i += 256){
    segp[i] = segp2d[(size_t)i*nbuck + b];
    segs[i] = lpos2d[(size_t)i*nbuck + b];
  }
  for (int i = t; i < nn; i += 256) lcnt[i] = 0;
  __syncthreads();

  // pass 1: count per node — one segment per thread, sequential march
  for (int i = t; i < nblk; i += 256){
    int d0 = segp[i];
    int d1 = (i + 1 < nblk) ? segp[i+1] : size;
    const int* src = ebuf + (size_t)i*BLKE + segs[i];
    for (int k = 0; k < d1 - d0; ++k)
      atomicAdd(&lcnt[src[k] & mask], 1);
  }
  __syncthreads();

  // emit degi/dis (coalesced), also for empty buckets
  for (int i = t; i < nn; i += 256){
    int c = lcnt[i];
    degi[n0 + i] = c;
    dis[n0 + i]  = rsqrtf((float)(c + 1));
  }
  // in-place exclusive scan of lcnt; emit offs
  int per = (nn + 255) >> 8;
  int myv[8];
  int s = 0;
  #pragma unroll
  for (int j = 0; j < 8; ++j){
    int i = t*per + j;
    int v = (j < per && i < nn) ? lcnt[i] : 0;
    myv[j] = v; s += v;
  }
  part[t] = s; __syncthreads();
  for (int off = 1; off < 256; off <<= 1){
    int a = part[t];
    int u = (t >= off) ? part[t-off] : 0;
    __syncthreads();
    part[t] = a + u;
    __syncthreads();
  }
  int run = part[t] - s;
  #pragma unroll
  for (int j = 0; j < 8; ++j){
    int i = t*per + j;
    if (j < per && i < nn){
      lcnt[i] = run;               // becomes cursor
      offs[n0 + i] = s0 + run;
      run += myv[j];
    }
  }
  __syncthreads();

  // pass 2: scatter rows by node (csr writes land in a 16KB L2-hot window)
  for (int i = t; i < nblk; i += 256){
    int d0 = segp[i];
    int d1 = (i + 1 < nblk) ? segp[i+1] : size;
    const int* src = ebuf + (size_t)i*BLKE + segs[i];
    for (int k = 0; k < d1 - d0; ++k){
      int v = src[k];
      int p = atomicAdd(&lcnt[v & mask], 1);
      csr[s0 + p] = v >> shift;
    }
  }
}

// ---- hs1 = dis * (x @ W1); BM=128 rows/block, BK=32, thread tile 2x4 ----
__global__ __launch_bounds__(256) void k_gemm1(const float* __restrict__ x, const float* __restrict__ W1,
                                               const float* __restrict__ dis, float* __restrict__ hs1, int N){
  __shared__ float xs[128*36];     // pad 32->36
  __shared__ float wc[32*16];
  int t  = threadIdx.x;
  int R0 = blockIdx.x*128;
  int lr = t >> 3;                 // 0..31
  int lc = (t & 7) * 4;            // 0..28
  int rt = t >> 2;                 // 0..63 -> rows rt*2+{0,1}
  int jq = t & 3;                  // col quad

  float4 acc0 = make_float4(0,0,0,0), acc1 = acc0;

  for (int kc = 0; kc < NF; kc += 32){
    #pragma unroll
    for (int li = 0; li < 4; ++li){
      int row = lr + li*32;
      int gr  = R0 + row;
      int grc = (gr < N) ? gr : 0;
      float4 v = *(const float4*)(x + (size_t)grc*NF + kc + lc);
      *(float4*)(xs + row*36 + lc) = v;
    }
    wc[t]       = W1[kc*16 + t];
    wc[t + 256] = W1[kc*16 + t + 256];
    __syncthreads();

    #pragma unroll
    for (int k0 = 0; k0 < 32; k0 += 4){
      float4 xr0 = *(const float4*)(xs + (rt*2+0)*36 + k0);
      float4 xr1 = *(const float4*)(xs + (rt*2+1)*36 + k0);
      float4 w0  = *(const float4*)(wc + (k0+0)*16 + jq*4);
      float4 w1  = *(const float4*)(wc + (k0+1)*16 + jq*4);
      float4 w2  = *(const float4*)(wc + (k0+2)*16 + jq*4);
      float4 w3  = *(const float4*)(wc + (k0+3)*16 + jq*4);
      acc0 = f4fma(acc0, xr0.x, w0); acc0 = f4fma(acc0, xr0.y, w1); acc0 = f4fma(acc0, xr0.z, w2); acc0 = f4fma(acc0, xr0.w, w3);
      acc1 = f4fma(acc1, xr1.x, w0); acc1 = f4fma(acc1, xr1.y, w1); acc1 = f4fma(acc1, xr1.z, w2); acc1 = f4fma(acc1, xr1.w, w3);
    }
    __syncthreads();
  }

  #pragma unroll
  for (int m = 0; m < 2; ++m){
    int gr = R0 + rt*2 + m;
    if (gr < N){
      float d = dis[gr];
      float4 a = (m==0) ? acc0 : acc1;
      float4 o = make_float4(a.x*d, a.y*d, a.z*d, a.w*d);
      *(float4*)(hs1 + (size_t)gr*16 + jq*4) = o;
    }
  }
}

// ---- layer1 aggregate + bias/ReLU + layer2 transform; 4 threads/node ----
__global__ __launch_bounds__(256) void k_agg1(const float* __restrict__ hs1, const int* __restrict__ offs,
                                              const int* __restrict__ degi, const int* __restrict__ csr,
                                              const float* __restrict__ dis, const float* __restrict__ b1,
                                              const float* __restrict__ W2, float* __restrict__ hs2, int N){
  __shared__ float sW[112];
  __shared__ float sb[16];
  int t = threadIdx.x;
  if (t < 112) sW[t] = W2[t];
  if (t < 16)  sb[t] = b1[t];
  __syncthreads();

  int g = blockIdx.x*256 + t;
  int n = g >> 2, q = g & 3;
  if (n >= N) return;

  const float4* h4 = (const float4*)hs1;
  float4 a0 = h4[(size_t)n*4 + q];          // self-loop init
  float4 a1 = make_float4(0,0,0,0);
  int st = offs[n], cnt = degi[n];
  int i = 0;
  for (; i + 2 <= cnt; i += 2){
    int s0c = csr[st + i];
    int s1c = csr[st + i + 1];
    float4 v0 = h4[(size_t)s0c*4 + q];
    float4 v1 = h4[(size_t)s1c*4 + q];
    a0 = f4add(a0, v0);
    a1 = f4add(a1, v1);
  }
  if (i < cnt) a0 = f4add(a0, h4[(size_t)csr[st + i]*4 + q]);
  a0 = f4add(a0, a1);

  float d = dis[n];
  float h0 = fmaxf(fmaf(d, a0.x, sb[q*4+0]), 0.f);
  float h1 = fmaxf(fmaf(d, a0.y, sb[q*4+1]), 0.f);
  float h2 = fmaxf(fmaf(d, a0.z, sb[q*4+2]), 0.f);
  float h3 = fmaxf(fmaf(d, a0.w, sb[q*4+3]), 0.f);

  float acc[7];
  int j = q*4;
  #pragma unroll
  for (int c = 0; c < 7; ++c){
    acc[c] = fmaf(h0, sW[(j+0)*7+c], fmaf(h1, sW[(j+1)*7+c], fmaf(h2, sW[(j+2)*7+c], h3*sW[(j+3)*7+c])));
  }
  #pragma unroll
  for (int c = 0; c < 7; ++c){
    acc[c] += __shfl_xor(acc[c], 1);
    acc[c] += __shfl_xor(acc[c], 2);
  }

  if (q == 0){
    *(float4*)(hs2 + (size_t)n*8) = make_float4(acc[0]*d, acc[1]*d, acc[2]*d, acc[3]*d);
  } else if (q == 1){
    *(float4*)(hs2 + (size_t)n*8 + 4) = make_float4(acc[4]*d, acc[5]*d, acc[6]*d, 0.f);
  }
}

// ---- layer2 aggregate + bias -> out. 2 threads/node, unroll 2 ----
__global__ __launch_bounds__(256) void k_agg2(const float* __restrict__ hs2, const int* __restrict__ offs,
                                              const int* __restrict__ degi, const int* __restrict__ csr,
                                              const float* __restrict__ dis, const float* __restrict__ b2,
                                              float* __restrict__ out, int N){
  int g = blockIdx.x*256 + threadIdx.x;
  int n = g >> 1, q = g & 1;
  if (n >= N) return;
  const float4* h4 = (const float4*)hs2;
  float4 a0 = h4[(size_t)n*2 + q];          // self-loop init
  float4 a1 = make_float4(0,0,0,0);
  int st = offs[n], cnt = degi[n];
  int i = 0;
  for (; i + 2 <= cnt; i += 2){
    int s0c = csr[st + i];
    int s1c = csr[st + i + 1];
    a0 = f4add(a0, h4[(size_t)s0c*2 + q]);
    a1 = f4add(a1, h4[(size_t)s1c*2 + q]);
  }
  if (i < cnt) a0 = f4add(a0, h4[(size_t)csr[st + i]*2 + q]);
  a0 = f4add(a0, a1);

  float d = dis[n];
  float* o = out + (size_t)n*7 + q*4;
  if (q == 0){
    o[0] = fmaf(d, a0.x, b2[0]);
    o[1] = fmaf(d, a0.y, b2[1]);
    o[2] = fmaf(d, a0.z, b2[2]);
    o[3] = fmaf(d, a0.w, b2[3]);
  } else {
    o[0] = fmaf(d, a0.x, b2[4]);
    o[1] = fmaf(d, a0.y, b2[5]);
    o[2] = fmaf(d, a0.z, b2[6]);
  }
}

extern "C" void kernel_launch(void* const* d_in, const int* in_sizes, int n_in,
                              void* d_out, int out_size, void* d_ws, size_t ws_size,
                              hipStream_t stream){
  const float* x  = (const float*)d_in[0];
  const int*   ei = (const int*)d_in[1];
  const float* W1 = (const float*)d_in[2];
  const float* b1 = (const float*)d_in[3];
  const float* W2 = (const float*)d_in[4];
  const float* b2 = (const float*)d_in[5];
  float* out = (float*)d_out;

  const int N = in_sizes[0] / NF;      // 100000
  const int E = in_sizes[1] / 2;       // 3200000

  // bucket geometry: npb = power-of-2 nodes/bucket, nbuck <= 2048
  int shift = 7;
  while (((N + (1 << shift) - 1) >> shift) > 2048) ++shift;
  const int npb   = 1 << shift;
  const int nbuck = (N + npb - 1) >> shift;
  const int nblk  = (E + BLKE - 1) / BLKE;   // <= 2048 for E <= 16.7M

  // ws carve-up (256B aligned)
  char* w = (char*)d_ws;
  size_t cur = 0;
  auto alloc = [&](size_t bytes)->char*{ char* p = w + cur; cur += (bytes + 255) & ~(size_t)255; return p; };
  int*   flag   = (int*)  alloc(256);
  int*   cnt2d  = (int*)  alloc((size_t)nblk*nbuck*4);
  int*   lpos2d = (int*)  alloc((size_t)nblk*nbuck*4);
  int*   btot   = (int*)  alloc((size_t)(nbuck+1)*4);
  int*   ebase  = (int*)  alloc((size_t)(nbuck+1)*4);
  int*   degi   = (int*)  alloc((size_t)N*4);
  float* dis    = (float*)alloc((size_t)N*4);
  int*   offs   = (int*)  alloc((size_t)N*4);
  int*   ebuf   = (int*)  alloc((size_t)nblk*BLKE*4);
  int*   csr    = (int*)  alloc((size_t)E*4);
  float* hs1    = (float*)alloc((size_t)N*16*4);
  float* hs2    = (float*)alloc((size_t)N*8*4);
  (void)ws_size; (void)n_in; (void)out_size;

  int gM  = (N + 127) / 128;
  int g2N = (2*N + 255) / 256;
  int g4N = (4*N + 255) / 256;

  k_detect<<<1, 256, 0, stream>>>(ei, flag);
  k_blocal<<<nblk, 256, 0, stream>>>(ei, flag, E, nbuck, shift, ebuf, cnt2d, lpos2d);
  k_cscan <<<nbuck, 256, 0, stream>>>(cnt2d, nblk, nbuck, btot);
  k_bscan <<<1, 256, 0, stream>>>(btot, nbuck, ebase);
  k_bsort <<<nbuck, 256, 0, stream>>>(ebuf, cnt2d, lpos2d, ebase, degi, dis, offs, csr,
                                      N, npb, shift, nblk, nbuck);
  k_gemm1 <<<gM, 256, 0, stream>>>(x, W1, dis, hs1, N);
  k_agg1  <<<g4N, 256, 0, stream>>>(hs1, offs, degi, csr, dis, b1, W2, hs2, N);
  k_agg2  <<<g2N, 256, 0, stream>>>(hs2, offs, degi, csr, dis, b2, out, N);
}